// Round 5
// baseline (246.371 us; speedup 1.0000x reference)
//
#include <hip/hip_runtime.h>
#include <hip/hip_bf16.h>
#include <math.h>

typedef __bf16 bf16;
typedef __bf16 bf16x4 __attribute__((ext_vector_type(4)));
typedef __bf16 bf16x8 __attribute__((ext_vector_type(8)));
typedef float  f32x4  __attribute__((ext_vector_type(4)));
typedef float  f32x16 __attribute__((ext_vector_type(16)));

#define S_LEN 2048
#define EMB   2048
#define NH    16
#define NKV   4
#define HD    128
#define FQKV  3072  /* NH*HD + 2*NKV*HD */
#define NSPLIT 2    /* cross-block KV splits */

__device__ __forceinline__ f32x4 mfma16(bf16x8 a, bf16x8 b, f32x4 c) {
  return __builtin_amdgcn_mfma_f32_16x16x32_bf16(a, b, c, 0, 0, 0);
}
__device__ __forceinline__ f32x16 mfma32(bf16x8 a, bf16x8 b, f32x16 c) {
  return __builtin_amdgcn_mfma_f32_32x32x16_bf16(a, b, c, 0, 0, 0);
}
__device__ __forceinline__ f32x16 zero16() {
  f32x16 v;
#pragma unroll
  for (int i = 0; i < 16; ++i) v[i] = 0.f;
  return v;
}

// ---------------- f32 -> bf16 convert, 4-wide ----------------
__global__ void cvt_kernel(const float* __restrict__ in, bf16* __restrict__ out, int n4) {
  int i = blockIdx.x * blockDim.x + threadIdx.x;
  const int stride = gridDim.x * blockDim.x;
  for (; i < n4; i += stride) {
    float4 v = reinterpret_cast<const float4*>(in)[i];
    bf16x4 o;
    o[0] = (bf16)v.x; o[1] = (bf16)v.y; o[2] = (bf16)v.z; o[3] = (bf16)v.w;
    reinterpret_cast<bf16x4*>(out)[i] = o;
  }
}

// ---------------- GEMM: C[M][N] = A[M][K] * B[N][K]^T (both row-major in K) ----------------
// mode 0: fused RoPE/split epilogue -> qb[h][s][d], kb[kh][s][d],
//         vtb = V in PV-fragment-ready layout: vf[kh][tile][d][32 perm kv]
// mode 1: plain f32 store to outf[row*N + col]
__global__ __launch_bounds__(256, 2) void gemm_bt(
    const bf16* __restrict__ A, const bf16* __restrict__ B,
    int M, int N, int K, int mode,
    bf16* __restrict__ qb, bf16* __restrict__ kb, bf16* __restrict__ vtb,
    float* __restrict__ outf)
{
  __shared__ __align__(16) bf16 As[128 * 64];
  __shared__ __align__(16) bf16 Bs[128 * 64];
  const int tid = threadIdx.x;
  const int w  = tid >> 6;
  const int l  = tid & 63;
  const int li = l & 15, lh = l >> 4;
  const int m0 = blockIdx.y * 128, n0 = blockIdx.x * 128;

  f32x4 acc[2][8];
#pragma unroll
  for (int i = 0; i < 2; ++i)
#pragma unroll
    for (int j = 0; j < 8; ++j) acc[i][j] = f32x4{0.f, 0.f, 0.f, 0.f};

  const int srow = l >> 3;   // row within an 8-row staging group
  const int schk = l & 7;    // 16B chunk within a 64-col row

  for (int k0 = 0; k0 < K; k0 += 64) {
#pragma unroll
    for (int i = 0; i < 4; ++i) {
      const int row = i * 32 + w * 8 + srow;
      const int sch = schk ^ (row & 7);
      const bf16* ga = A + (size_t)(m0 + row) * K + (k0 + sch * 8);
      const bf16* gb = B + (size_t)(n0 + row) * K + (k0 + sch * 8);
      bf16* la = As + (i * 32 + w * 8) * 64;
      bf16* lb = Bs + (i * 32 + w * 8) * 64;
      __builtin_amdgcn_global_load_lds((const __attribute__((address_space(1))) void*)ga,
                                       (__attribute__((address_space(3))) void*)la, 16, 0, 0);
      __builtin_amdgcn_global_load_lds((const __attribute__((address_space(1))) void*)gb,
                                       (__attribute__((address_space(3))) void*)lb, 16, 0, 0);
    }
    __syncthreads();
#pragma unroll
    for (int kc = 0; kc < 2; ++kc) {
      bf16x8 afr[2], bfr[8];
#pragma unroll
      for (int mt = 0; mt < 2; ++mt) {
        const int mr = w * 32 + mt * 16 + li;
        const int c  = (kc * 4 + lh) ^ (mr & 7);
        afr[mt] = *reinterpret_cast<const bf16x8*>((const char*)As + mr * 128 + c * 16);
      }
#pragma unroll
      for (int nt = 0; nt < 8; ++nt) {
        const int nr = nt * 16 + li;
        const int c  = (kc * 4 + lh) ^ (nr & 7);
        bfr[nt] = *reinterpret_cast<const bf16x8*>((const char*)Bs + nr * 128 + c * 16);
      }
#pragma unroll
      for (int nt = 0; nt < 8; ++nt) {
        acc[0][nt] = mfma16(afr[0], bfr[nt], acc[0][nt]);
        acc[1][nt] = mfma16(afr[1], bfr[nt], acc[1][nt]);
      }
    }
    __syncthreads();
  }

  // ---- epilogue ----
  const int row_base = m0 + w * 32;
  if (mode == 1) {
#pragma unroll
    for (int mt = 0; mt < 2; ++mt)
#pragma unroll
      for (int nt = 0; nt < 8; ++nt)
#pragma unroll
        for (int r = 0; r < 4; ++r) {
          const int sr = row_base + mt * 16 + lh * 4 + r;
          const int sc = n0 + nt * 16 + li;
          outf[(size_t)sr * N + sc] = acc[mt][nt][r];
        }
  } else {
    int seg, hh;
    if (n0 < NH * HD)            { seg = 0; hh = n0 >> 7; }
    else if (n0 < (NH + NKV) * HD){ seg = 1; hh = (n0 - NH * HD) >> 7; }
    else                          { seg = 2; hh = (n0 - (NH + NKV) * HD) >> 7; }

    if (seg == 2) {
      // V -> fragment-ready layout vf[kh][T][d][32]:
      // elems [0..7]=kv{0-3,8-11}, [8..15]={16-19,24-27}, [16..23]={4-7,12-15}, [24..31]={20-23,28-31}
      const int T = row_base >> 5;            // 32-row kv tile (same for mt=0,1)
#pragma unroll
      for (int mt = 0; mt < 2; ++mt) {
        const int qp = mt * 4 + lh;           // ss>>2, ss = mt*16+lh*4+r
        const int pq = (qp >> 1) + (qp & 1) * 4;
#pragma unroll
        for (int nt = 0; nt < 8; ++nt) {
          const int d = nt * 16 + li;
          bf16x4 pk;
#pragma unroll
          for (int r = 0; r < 4; ++r) pk[r] = (bf16)acc[mt][nt][r];
          *reinterpret_cast<bf16x4*>(
              vtb + ((size_t)(hh * 64 + T) * 128 + d) * 32 + pq * 4) = pk;
        }
      }
    } else {  // Q or K: RoPE (+ 1/sqrt(D) folded into Q)
      float invf[4];
#pragma unroll
      for (int j = 0; j < 4; ++j)
        invf[j] = exp2f(-(float)(j * 16 + li) * (13.287712379549449f / 64.0f)); // 10000^(-i/64)
      bf16* dst = (seg == 0) ? (qb + (size_t)hh * S_LEN * HD)
                             : (kb + (size_t)hh * S_LEN * HD);
      const float qscale = (seg == 0) ? 0.08838834764831845f : 1.0f;
#pragma unroll
      for (int mt = 0; mt < 2; ++mt)
#pragma unroll
        for (int r = 0; r < 4; ++r) {
          const int spos = row_base + mt * 16 + lh * 4 + r;
          float cs[4], sn[4];
#pragma unroll
          for (int j = 0; j < 4; ++j) sincosf((float)spos * invf[j], &sn[j], &cs[j]);
#pragma unroll
          for (int nt = 0; nt < 8; ++nt) {
            const int d = nt * 16 + li;
            const int j = nt & 3;
            const float x = acc[mt][nt][r];
            const float prt = acc[mt][nt ^ 4][r];
            const float rot = (nt < 4) ? -prt : prt;
            const float y = (x * cs[j] + rot * sn[j]) * qscale;
            dst[(size_t)spos * HD + d] = (bf16)y;
          }
        }
    }
  }
}

// ---------------- flash attention, swapped-QK^T 32x32, 8-way KV split ----------------
// Grid (64 q-tiles, 16 heads, NSPLIT). Block (t,h,p): its 4 waves take kv-tiles
// j with j mod 8 == 4p+w. Block-level partial (O numerator bf16, m, l) goes to
// global Opart/mlbuf; attn_merge_kernel combines the NSPLIT partials.
__global__ __launch_bounds__(256, 4) void attn_kernel(
    const bf16* __restrict__ qb, const bf16* __restrict__ kb, const bf16* __restrict__ vtb,
    bf16* __restrict__ Opart, float* __restrict__ mlbuf)
{
  __shared__ float Ml[4][32], Ll[4][32];
  __shared__ float Obuf[32][129];   // stride 129: conflict-free column writes

  const int tid = threadIdx.x;
  const int w  = tid >> 6;
  const int l  = tid & 63;
  const int lq = l & 31;     // q index within tile (C col / B row)
  const int hi = l >> 5;     // lane half (C row group / k-slot group)
  const int qt = (int)gridDim.x - 1 - (int)blockIdx.x;  // longest first
  const int q0 = qt * 32;
  const int h  = blockIdx.y;
  const int p  = blockIdx.z;
  const int kh = h >> 2;     // rep = 4

  const bf16* Qh = qb + (size_t)h * S_LEN * HD;
  const bf16* Kh = kb + (size_t)kh * S_LEN * HD;
  const bf16* Vf = vtb + (size_t)kh * S_LEN * HD;   // fragment-ready layout

  const float L2E = 1.4426950408889634f;
  const float BIG = -3.0e38f;   // finite mask value: no NaN paths

  // hoist Q fragments: lane -> q-row (q0+lq), d = kc*16 + hi*8 + {0..7}
  bf16x8 qfr[8];
#pragma unroll
  for (int kc = 0; kc < 8; ++kc)
    qfr[kc] = *reinterpret_cast<const bf16x8*>(Qh + (size_t)(q0 + lq) * HD + kc * 16 + hi * 8);

  f32x16 o[4];
#pragma unroll
  for (int dt = 0; dt < 4; ++dt) o[dt] = zero16();
  float mrow = BIG, lrow = 0.f;

  for (int kv0 = (4 * p + w) * 32; kv0 < q0 + 32; kv0 += 32 * 4 * NSPLIT) {
    // ---- QK^T: S^T[kv][q], two chains of 4 ----
    f32x16 sa = zero16(), sb = zero16();
#pragma unroll
    for (int kc = 0; kc < 4; ++kc) {
      bf16x8 kfa = *reinterpret_cast<const bf16x8*>(
          Kh + (size_t)(kv0 + lq) * HD + kc * 16 + hi * 8);
      bf16x8 kfb = *reinterpret_cast<const bf16x8*>(
          Kh + (size_t)(kv0 + lq) * HD + (kc + 4) * 16 + hi * 8);
      sa = mfma32(kfa, qfr[kc], sa);
      sb = mfma32(kfb, qfr[kc + 4], sb);
    }
    f32x16 s = sa + sb;
    // ---- causal mask (diagonal tiles only) ----
    const int q = q0 + lq;
    if (kv0 + 31 > q0) {
#pragma unroll
      for (int r = 0; r < 16; ++r) {
        const int kvv = (r & 3) + 8 * (r >> 2) + 4 * hi;
        if (kv0 + kvv > q) s[r] = BIG;
      }
    }
    // ---- in-register online softmax with defer-max (THR=8) ----
    float pm = s[0];
#pragma unroll
    for (int r = 1; r < 16; ++r) pm = fmaxf(pm, s[r]);
    pm = fmaxf(pm, __shfl_xor(pm, 32));
    if (__any(pm > mrow + 8.f)) {
      const float mnew = fmaxf(mrow, pm);
      const float sc = (mrow < -1.0e37f) ? 0.f : exp2f((mrow - mnew) * L2E);
      mrow = mnew;
      lrow *= sc;
#pragma unroll
      for (int dt = 0; dt < 4; ++dt) o[dt] = o[dt] * sc;
    }
    bf16x8 pb0, pb1;
    float tsum = 0.f;
#pragma unroll
    for (int r = 0; r < 8; ++r) {
      const float pv = exp2f((s[r] - mrow) * L2E);
      tsum += pv; pb0[r] = (bf16)pv;
    }
#pragma unroll
    for (int r = 0; r < 8; ++r) {
      const float pv = exp2f((s[8 + r] - mrow) * L2E);
      tsum += pv; pb1[r] = (bf16)pv;
    }
    tsum += __shfl_xor(tsum, 32);
    lrow += tsum;
    // ---- PV: O^T[d][q] += V^T[d][kv] * P, fragment-ready V ----
    const bf16* vbase = Vf + ((size_t)(kv0 >> 5) * 128 + lq) * 32 + hi * 16;
#pragma unroll
    for (int dt = 0; dt < 4; ++dt) {
      const bf16* vrow = vbase + (size_t)(dt * 32) * 32;
      bf16x8 A1 = *reinterpret_cast<const bf16x8*>(vrow);
      bf16x8 A2 = *reinterpret_cast<const bf16x8*>(vrow + 8);
      o[dt] = mfma32(A1, pb0, o[dt]);
      o[dt] = mfma32(A2, pb1, o[dt]);
    }
  }

  // ---- merge the 4 per-wave partials into a block-level partial ----
  if (hi == 0) { Ml[w][lq] = mrow; Ll[w][lq] = lrow; }
  __syncthreads();
  const float m0v = Ml[0][lq], m1v = Ml[1][lq], m2v = Ml[2][lq], m3v = Ml[3][lq];
  const float mg = fmaxf(fmaxf(m0v, m1v), fmaxf(m2v, m3v));
  const float lg = Ll[0][lq] * exp2f((m0v - mg) * L2E)
                 + Ll[1][lq] * exp2f((m1v - mg) * L2E)
                 + Ll[2][lq] * exp2f((m2v - mg) * L2E)
                 + Ll[3][lq] * exp2f((m3v - mg) * L2E);
  const float sc2 = (mrow < -1.0e37f) ? 0.f : exp2f((mrow - mg) * L2E);
  if (w == 0 && hi == 0) {
    reinterpret_cast<float2*>(mlbuf)[(size_t)p * (NH * S_LEN) + h * S_LEN + q0 + lq] =
        make_float2(mg, lg);
  }
#pragma unroll
  for (int pass = 0; pass < 4; ++pass) {
    if (w == pass) {
#pragma unroll
      for (int dt = 0; dt < 4; ++dt)
#pragma unroll
        for (int r = 0; r < 16; ++r) {
          const int d = dt * 32 + (r & 3) + 8 * (r >> 2) + 4 * hi;
          const float v = o[dt][r] * sc2;
          if (pass == 0) Obuf[lq][d] = v; else Obuf[lq][d] += v;
        }
    }
    __syncthreads();
  }
  // ---- write block partial O (numerator, bf16): row = tid>>3, 16 d each ----
  {
    const int row = tid >> 3;
    const int d0 = (tid & 7) * 16;
    bf16x8 pk0, pk1;
#pragma unroll
    for (int j = 0; j < 8; ++j) {
      pk0[j] = (bf16)Obuf[row][d0 + j];
      pk1[j] = (bf16)Obuf[row][d0 + 8 + j];
    }
    bf16* dst = Opart + ((size_t)p * (NH * S_LEN) + h * S_LEN + q0 + row) * HD + d0;
    *reinterpret_cast<bf16x8*>(dst) = pk0;
    *reinterpret_cast<bf16x8*>(dst + 8) = pk1;
  }
}

// ---------------- merge NSPLIT partials -> ctx[q][h*HD+d] bf16 ----------------
// 8 rows per 256-thread block; 32 threads/row, 4 d each.
__global__ __launch_bounds__(256) void attn_merge_kernel(
    const bf16* __restrict__ Opart, const float* __restrict__ mlbuf,
    bf16* __restrict__ ctx)
{
  const int tid = threadIdx.x;
  const int r = blockIdx.x * 8 + (tid >> 5);        // r = h*S_LEN + q
  const int h = r >> 11, q = r & (S_LEN - 1);
  const int d = (tid & 31) * 4;
  const float L2E = 1.4426950408889634f;
  const float2 ml0 = reinterpret_cast<const float2*>(mlbuf)[r];
  const float2 ml1 = reinterpret_cast<const float2*>(mlbuf)[NH * S_LEN + r];
  const float mg = fmaxf(ml0.x, ml1.x);
  const float e0 = exp2f((ml0.x - mg) * L2E);
  const float e1 = exp2f((ml1.x - mg) * L2E);
  const float linv = 1.0f / (ml0.y * e0 + ml1.y * e1);
  bf16x4 o0 = *reinterpret_cast<const bf16x4*>(Opart + (size_t)r * HD + d);
  bf16x4 o1 = *reinterpret_cast<const bf16x4*>(Opart + (size_t)(NH * S_LEN) * HD + (size_t)r * HD + d);
  bf16x4 outv;
#pragma unroll
  for (int j = 0; j < 4; ++j)
    outv[j] = (bf16)(((float)o0[j] * e0 + (float)o1[j] * e1) * linv);
  *reinterpret_cast<bf16x4*>(ctx + (size_t)q * (NH * HD) + h * HD + d) = outv;
}

extern "C" void kernel_launch(void* const* d_in, const int* in_sizes, int n_in,
                              void* d_out, int out_size, void* d_ws, size_t ws_size,
                              hipStream_t stream)
{
  const float* x       = (const float*)d_in[0];
  const float* w_qkv   = (const float*)d_in[1];
  const float* w_dense = (const float*)d_in[2];
  float* out = (float*)d_out;

  char* ws = (char*)d_ws;
  size_t off = 0;
  bf16* xb    = (bf16*)(ws + off); off += (size_t)S_LEN * EMB * 2;      //  8.4 MB
  bf16* wqkvb = (bf16*)(ws + off); off += (size_t)FQKV * EMB * 2;       // 12.6 MB
  bf16* wdb   = (bf16*)(ws + off); off += (size_t)EMB * EMB * 2;
  bf16* qbuf  = (bf16*)(ws + off); off += (size_t)NH  * S_LEN * HD * 2;
  bf16* kbuf  = (bf16*)(ws + off); off += (size_t)NKV * S_LEN * HD * 2;
  bf16* vfbuf = (bf16*)(ws + off); off += (size_t)NKV * HD * S_LEN * 2;
  bf16* ctxb  = (bf16*)(ws + off); off += (size_t)S_LEN * NH * HD * 2;
  // Attention partials alias the [xb, wqkvb) region (dead after QKV GEMM):
  // Opart: NSPLIT*16*2048*128 bf16 = 16.78 MB; mlbuf: NSPLIT*16*2048*2 f32 = 1.05 MB
  bf16*  opart = (bf16*)ws;
  float* mlbuf = (float*)(ws + (size_t)NSPLIT * NH * S_LEN * HD * 2);
  (void)ws_size; (void)in_sizes; (void)n_in; (void)out_size;

  cvt_kernel<<<2048, 256, 0, stream>>>(x,       xb,    S_LEN * EMB / 4);
  cvt_kernel<<<2048, 256, 0, stream>>>(w_qkv,   wqkvb, FQKV * EMB / 4);
  cvt_kernel<<<2048, 256, 0, stream>>>(w_dense, wdb,   EMB * EMB / 4);

  gemm_bt<<<dim3(FQKV / 128, S_LEN / 128), 256, 0, stream>>>(
      xb, wqkvb, S_LEN, FQKV, EMB, 0, qbuf, kbuf, vfbuf, nullptr);

  attn_kernel<<<dim3(S_LEN / 32, NH, NSPLIT), 256, 0, stream>>>(
      qbuf, kbuf, vfbuf, opart, mlbuf);

  attn_merge_kernel<<<(NH * S_LEN) / 8, 256, 0, stream>>>(opart, mlbuf, ctxb);

  gemm_bt<<<dim3(EMB / 128, S_LEN / 128), 256, 0, stream>>>(
      ctxb, wdb, S_LEN, EMB, NH * HD, 1, nullptr, nullptr, nullptr, out);
}

// Round 6
// 192.146 us; speedup vs baseline: 1.2822x; 1.2822x over previous
//
#include <hip/hip_runtime.h>
#include <hip/hip_bf16.h>
#include <math.h>

typedef __bf16 bf16;
typedef __bf16 bf16x4 __attribute__((ext_vector_type(4)));
typedef __bf16 bf16x8 __attribute__((ext_vector_type(8)));
typedef float  f32x4  __attribute__((ext_vector_type(4)));
typedef float  f32x16 __attribute__((ext_vector_type(16)));

#define S_LEN 2048
#define EMB   2048
#define NH    16
#define NKV   4
#define HD    128
#define FQKV  3072  /* NH*HD + 2*NKV*HD */

__device__ __forceinline__ f32x4 mfma16(bf16x8 a, bf16x8 b, f32x4 c) {
  return __builtin_amdgcn_mfma_f32_16x16x32_bf16(a, b, c, 0, 0, 0);
}
__device__ __forceinline__ f32x16 mfma32(bf16x8 a, bf16x8 b, f32x16 c) {
  return __builtin_amdgcn_mfma_f32_32x32x16_bf16(a, b, c, 0, 0, 0);
}
__device__ __forceinline__ f32x16 zero16() {
  f32x16 v;
#pragma unroll
  for (int i = 0; i < 16; ++i) v[i] = 0.f;
  return v;
}

// ---------------- f32 -> bf16 convert, 4-wide ----------------
__global__ void cvt_kernel(const float* __restrict__ in, bf16* __restrict__ out, int n4) {
  int i = blockIdx.x * blockDim.x + threadIdx.x;
  const int stride = gridDim.x * blockDim.x;
  for (; i < n4; i += stride) {
    float4 v = reinterpret_cast<const float4*>(in)[i];
    bf16x4 o;
    o[0] = (bf16)v.x; o[1] = (bf16)v.y; o[2] = (bf16)v.z; o[3] = (bf16)v.w;
    reinterpret_cast<bf16x4*>(out)[i] = o;
  }
}

// ---------------- GEMM: C[M][N] = A[M][K] * B[N][K]^T (both row-major in K) ----------------
// mode 0: fused RoPE/split epilogue -> qb[h][s][d], kb[kh][s][d],
//         vtb = V in PV-fragment-ready layout: vf[kh][tile][d][32 perm kv]
// mode 1: plain f32 store to outf[row*N + col]
__global__ __launch_bounds__(256, 2) void gemm_bt(
    const bf16* __restrict__ A, const bf16* __restrict__ B,
    int M, int N, int K, int mode,
    bf16* __restrict__ qb, bf16* __restrict__ kb, bf16* __restrict__ vtb,
    float* __restrict__ outf)
{
  __shared__ __align__(16) bf16 As[128 * 64];
  __shared__ __align__(16) bf16 Bs[128 * 64];
  const int tid = threadIdx.x;
  const int w  = tid >> 6;
  const int l  = tid & 63;
  const int li = l & 15, lh = l >> 4;
  const int m0 = blockIdx.y * 128, n0 = blockIdx.x * 128;

  f32x4 acc[2][8];
#pragma unroll
  for (int i = 0; i < 2; ++i)
#pragma unroll
    for (int j = 0; j < 8; ++j) acc[i][j] = f32x4{0.f, 0.f, 0.f, 0.f};

  const int srow = l >> 3;   // row within an 8-row staging group
  const int schk = l & 7;    // 16B chunk within a 64-col row

  for (int k0 = 0; k0 < K; k0 += 64) {
#pragma unroll
    for (int i = 0; i < 4; ++i) {
      const int row = i * 32 + w * 8 + srow;
      const int sch = schk ^ (row & 7);
      const bf16* ga = A + (size_t)(m0 + row) * K + (k0 + sch * 8);
      const bf16* gb = B + (size_t)(n0 + row) * K + (k0 + sch * 8);
      bf16* la = As + (i * 32 + w * 8) * 64;
      bf16* lb = Bs + (i * 32 + w * 8) * 64;
      __builtin_amdgcn_global_load_lds((const __attribute__((address_space(1))) void*)ga,
                                       (__attribute__((address_space(3))) void*)la, 16, 0, 0);
      __builtin_amdgcn_global_load_lds((const __attribute__((address_space(1))) void*)gb,
                                       (__attribute__((address_space(3))) void*)lb, 16, 0, 0);
    }
    __syncthreads();
#pragma unroll
    for (int kc = 0; kc < 2; ++kc) {
      bf16x8 afr[2], bfr[8];
#pragma unroll
      for (int mt = 0; mt < 2; ++mt) {
        const int mr = w * 32 + mt * 16 + li;
        const int c  = (kc * 4 + lh) ^ (mr & 7);
        afr[mt] = *reinterpret_cast<const bf16x8*>((const char*)As + mr * 128 + c * 16);
      }
#pragma unroll
      for (int nt = 0; nt < 8; ++nt) {
        const int nr = nt * 16 + li;
        const int c  = (kc * 4 + lh) ^ (nr & 7);
        bfr[nt] = *reinterpret_cast<const bf16x8*>((const char*)Bs + nr * 128 + c * 16);
      }
#pragma unroll
      for (int nt = 0; nt < 8; ++nt) {
        acc[0][nt] = mfma16(afr[0], bfr[nt], acc[0][nt]);
        acc[1][nt] = mfma16(afr[1], bfr[nt], acc[1][nt]);
      }
    }
    __syncthreads();
  }

  // ---- epilogue ----
  const int row_base = m0 + w * 32;
  if (mode == 1) {
#pragma unroll
    for (int mt = 0; mt < 2; ++mt)
#pragma unroll
      for (int nt = 0; nt < 8; ++nt)
#pragma unroll
        for (int r = 0; r < 4; ++r) {
          const int sr = row_base + mt * 16 + lh * 4 + r;
          const int sc = n0 + nt * 16 + li;
          outf[(size_t)sr * N + sc] = acc[mt][nt][r];
        }
  } else {
    int seg, hh;
    if (n0 < NH * HD)            { seg = 0; hh = n0 >> 7; }
    else if (n0 < (NH + NKV) * HD){ seg = 1; hh = (n0 - NH * HD) >> 7; }
    else                          { seg = 2; hh = (n0 - (NH + NKV) * HD) >> 7; }

    if (seg == 2) {
      // V -> fragment-ready layout vf[kh][T][d][32]:
      // elems [0..7]=kv{0-3,8-11}, [8..15]={16-19,24-27}, [16..23]={4-7,12-15}, [24..31]={20-23,28-31}
      const int T = row_base >> 5;            // 32-row kv tile (same for mt=0,1)
#pragma unroll
      for (int mt = 0; mt < 2; ++mt) {
        const int qp = mt * 4 + lh;           // ss>>2, ss = mt*16+lh*4+r
        const int pq = (qp >> 1) + (qp & 1) * 4;
#pragma unroll
        for (int nt = 0; nt < 8; ++nt) {
          const int d = nt * 16 + li;
          bf16x4 pk;
#pragma unroll
          for (int r = 0; r < 4; ++r) pk[r] = (bf16)acc[mt][nt][r];
          *reinterpret_cast<bf16x4*>(
              vtb + ((size_t)(hh * 64 + T) * 128 + d) * 32 + pq * 4) = pk;
        }
      }
    } else {  // Q or K: RoPE (+ 1/sqrt(D) folded into Q)
      float invf[4];
#pragma unroll
      for (int j = 0; j < 4; ++j)
        invf[j] = exp2f(-(float)(j * 16 + li) * (13.287712379549449f / 64.0f)); // 10000^(-i/64)
      bf16* dst = (seg == 0) ? (qb + (size_t)hh * S_LEN * HD)
                             : (kb + (size_t)hh * S_LEN * HD);
      const float qscale = (seg == 0) ? 0.08838834764831845f : 1.0f;
#pragma unroll
      for (int mt = 0; mt < 2; ++mt)
#pragma unroll
        for (int r = 0; r < 4; ++r) {
          const int spos = row_base + mt * 16 + lh * 4 + r;
          float cs[4], sn[4];
#pragma unroll
          for (int j = 0; j < 4; ++j) sincosf((float)spos * invf[j], &sn[j], &cs[j]);
#pragma unroll
          for (int nt = 0; nt < 8; ++nt) {
            const int d = nt * 16 + li;
            const int j = nt & 3;
            const float x = acc[mt][nt][r];
            const float prt = acc[mt][nt ^ 4][r];
            const float rot = (nt < 4) ? -prt : prt;
            const float y = (x * cs[j] + rot * sn[j]) * qscale;
            dst[(size_t)spos * HD + d] = (bf16)y;
          }
        }
    }
  }
}

// ---------------- flash attention, swapped-QK^T 32x32 + in-block KV-split ----------------
// Block = 4 waves on the SAME 32 q-rows; wave w takes KV tiles kv0 = w*32 + 128t.
// Per-head qt rotation balances per-CU work (co-resident blocks get spread qt).
// Per KV-iteration: stage ALL K (8) and V (8) loads into registers first, then
// compute -> one memory wait per iteration instead of ~8 load->use stalls.
__global__ __launch_bounds__(256, 3) void attn_kernel(
    const bf16* __restrict__ qb, const bf16* __restrict__ kb, const bf16* __restrict__ vtb,
    bf16* __restrict__ ctx)
{
  __shared__ float Ml[4][32], Ll[4][32], Lgl[32];
  __shared__ float Obuf[32][129];   // stride 129: conflict-free column writes

  const int tid = threadIdx.x;
  const int w  = tid >> 6;
  const int l  = tid & 63;
  const int lq = l & 31;     // q index within tile (C col / B row)
  const int hi = l >> 5;     // lane half (C row group / k-slot group)
  const int h  = blockIdx.y;
  const int qt = ((int)blockIdx.x + 20 * h) & 63;   // per-head rotation: CU balance
  const int q0 = qt * 32;
  const int kh = h >> 2;     // rep = 4

  const bf16* Qh = qb + (size_t)h * S_LEN * HD;
  const bf16* Kh = kb + (size_t)kh * S_LEN * HD;
  const bf16* Vf = vtb + (size_t)kh * S_LEN * HD;   // fragment-ready layout

  const float L2E = 1.4426950408889634f;
  const float BIG = -3.0e38f;   // finite mask value: no NaN paths

  // hoist Q fragments: lane -> q-row (q0+lq), d = kc*16 + hi*8 + {0..7}
  bf16x8 qfr[8];
#pragma unroll
  for (int kc = 0; kc < 8; ++kc)
    qfr[kc] = *reinterpret_cast<const bf16x8*>(Qh + (size_t)(q0 + lq) * HD + kc * 16 + hi * 8);

  f32x16 o[4];
#pragma unroll
  for (int dt = 0; dt < 4; ++dt) o[dt] = zero16();
  float mrow = BIG, lrow = 0.f;

  for (int kv0 = w * 32; kv0 < q0 + 32; kv0 += 128) {
    // ---- stage all K and V fragments for this tile (16 loads, then compute) ----
    const bf16* krow_p = Kh + (size_t)(kv0 + lq) * HD + hi * 8;
    bf16x8 kf[8];
#pragma unroll
    for (int kc = 0; kc < 8; ++kc)
      kf[kc] = *reinterpret_cast<const bf16x8*>(krow_p + kc * 16);
    const bf16* vbase = Vf + ((size_t)(kv0 >> 5) * 128 + lq) * 32 + hi * 16;
    bf16x8 va[8];
#pragma unroll
    for (int dt = 0; dt < 4; ++dt) {
      va[2 * dt]     = *reinterpret_cast<const bf16x8*>(vbase + (size_t)(dt * 32) * 32);
      va[2 * dt + 1] = *reinterpret_cast<const bf16x8*>(vbase + (size_t)(dt * 32) * 32 + 8);
    }
    // ---- QK^T: S^T[kv][q], two chains of 4 ----
    f32x16 sa = zero16(), sb = zero16();
#pragma unroll
    for (int kc = 0; kc < 4; ++kc) {
      sa = mfma32(kf[kc], qfr[kc], sa);
      sb = mfma32(kf[kc + 4], qfr[kc + 4], sb);
    }
    f32x16 s = sa + sb;
    // ---- causal mask (diagonal tiles only) ----
    const int q = q0 + lq;
    if (kv0 + 31 > q0) {
#pragma unroll
      for (int r = 0; r < 16; ++r) {
        const int kvv = (r & 3) + 8 * (r >> 2) + 4 * hi;
        if (kv0 + kvv > q) s[r] = BIG;
      }
    }
    // ---- in-register online softmax with defer-max (THR=8) ----
    float pm = s[0];
#pragma unroll
    for (int r = 1; r < 16; ++r) pm = fmaxf(pm, s[r]);
    pm = fmaxf(pm, __shfl_xor(pm, 32));
    if (__any(pm > mrow + 8.f)) {
      const float mnew = fmaxf(mrow, pm);
      const float sc = (mrow < -1.0e37f) ? 0.f : exp2f((mrow - mnew) * L2E);
      mrow = mnew;
      lrow *= sc;
#pragma unroll
      for (int dt = 0; dt < 4; ++dt) o[dt] = o[dt] * sc;
    }
    bf16x8 pb0, pb1;
    float tsum = 0.f;
#pragma unroll
    for (int r = 0; r < 8; ++r) {
      const float pv = exp2f((s[r] - mrow) * L2E);
      tsum += pv; pb0[r] = (bf16)pv;
    }
#pragma unroll
    for (int r = 0; r < 8; ++r) {
      const float pv = exp2f((s[8 + r] - mrow) * L2E);
      tsum += pv; pb1[r] = (bf16)pv;
    }
    tsum += __shfl_xor(tsum, 32);
    lrow += tsum;
    // ---- PV: O^T[d][q] += V^T[d][kv] * P, staged V ----
#pragma unroll
    for (int dt = 0; dt < 4; ++dt) {
      o[dt] = mfma32(va[2 * dt], pb0, o[dt]);
      o[dt] = mfma32(va[2 * dt + 1], pb1, o[dt]);
    }
  }

  // ---- merge the 4 KV-split partials (shared Obuf, serialized passes) ----
  if (hi == 0) { Ml[w][lq] = mrow; Ll[w][lq] = lrow; }
  __syncthreads();
  const float m0v = Ml[0][lq], m1v = Ml[1][lq], m2v = Ml[2][lq], m3v = Ml[3][lq];
  const float mg = fmaxf(fmaxf(m0v, m1v), fmaxf(m2v, m3v));
  const float lg = Ll[0][lq] * exp2f((m0v - mg) * L2E)
                 + Ll[1][lq] * exp2f((m1v - mg) * L2E)
                 + Ll[2][lq] * exp2f((m2v - mg) * L2E)
                 + Ll[3][lq] * exp2f((m3v - mg) * L2E);
  const float sc2 = (mrow < -1.0e37f) ? 0.f : exp2f((mrow - mg) * L2E);
  if (w == 0 && hi == 0) Lgl[lq] = lg;
#pragma unroll
  for (int pass = 0; pass < 4; ++pass) {
    if (w == pass) {
#pragma unroll
      for (int dt = 0; dt < 4; ++dt)
#pragma unroll
        for (int r = 0; r < 16; ++r) {
          const int d = dt * 32 + (r & 3) + 8 * (r >> 2) + 4 * hi;
          const float v = o[dt][r] * sc2;
          if (pass == 0) Obuf[lq][d] = v; else Obuf[lq][d] += v;
        }
    }
    __syncthreads();
  }
  // ---- epilogue: 256 threads, row = tid>>3, 16 d each ----
  {
    const int row = tid >> 3;
    const int d0 = (tid & 7) * 16;
    const float linv = 1.0f / Lgl[row];
    bf16x8 pk0, pk1;
#pragma unroll
    for (int j = 0; j < 8; ++j) {
      pk0[j] = (bf16)(Obuf[row][d0 + j] * linv);
      pk1[j] = (bf16)(Obuf[row][d0 + 8 + j] * linv);
    }
    bf16* dst = ctx + (size_t)(q0 + row) * (NH * HD) + h * HD + d0;
    *reinterpret_cast<bf16x8*>(dst) = pk0;
    *reinterpret_cast<bf16x8*>(dst + 8) = pk1;
  }
}

extern "C" void kernel_launch(void* const* d_in, const int* in_sizes, int n_in,
                              void* d_out, int out_size, void* d_ws, size_t ws_size,
                              hipStream_t stream)
{
  const float* x       = (const float*)d_in[0];
  const float* w_qkv   = (const float*)d_in[1];
  const float* w_dense = (const float*)d_in[2];
  float* out = (float*)d_out;

  char* ws = (char*)d_ws;
  size_t off = 0;
  bf16* xb    = (bf16*)(ws + off); off += (size_t)S_LEN * EMB * 2;
  bf16* wqkvb = (bf16*)(ws + off); off += (size_t)FQKV * EMB * 2;
  bf16* wdb   = (bf16*)(ws + off); off += (size_t)EMB * EMB * 2;
  bf16* qbuf  = (bf16*)(ws + off); off += (size_t)NH  * S_LEN * HD * 2;
  bf16* kbuf  = (bf16*)(ws + off); off += (size_t)NKV * S_LEN * HD * 2;
  bf16* vfbuf = (bf16*)(ws + off); off += (size_t)NKV * HD * S_LEN * 2;
  bf16* ctxb  = (bf16*)(ws + off); off += (size_t)S_LEN * NH * HD * 2;
  (void)ws_size; (void)in_sizes; (void)n_in; (void)out_size;

  cvt_kernel<<<2048, 256, 0, stream>>>(x,       xb,    S_LEN * EMB / 4);
  cvt_kernel<<<2048, 256, 0, stream>>>(w_qkv,   wqkvb, FQKV * EMB / 4);
  cvt_kernel<<<2048, 256, 0, stream>>>(w_dense, wdb,   EMB * EMB / 4);

  gemm_bt<<<dim3(FQKV / 128, S_LEN / 128), 256, 0, stream>>>(
      xb, wqkvb, S_LEN, FQKV, EMB, 0, qbuf, kbuf, vfbuf, nullptr);

  attn_kernel<<<dim3(S_LEN / 32, NH), 256, 0, stream>>>(qbuf, kbuf, vfbuf, ctxb);

  gemm_bt<<<dim3(EMB / 128, S_LEN / 128), 256, 0, stream>>>(
      ctxb, wdb, S_LEN, EMB, NH * HD, 1, nullptr, nullptr, nullptr, out);
}

// Round 7
// 187.639 us; speedup vs baseline: 1.3130x; 1.0240x over previous
//
#include <hip/hip_runtime.h>
#include <hip/hip_bf16.h>
#include <math.h>

typedef __bf16 bf16;
typedef __bf16 bf16x4 __attribute__((ext_vector_type(4)));
typedef __bf16 bf16x8 __attribute__((ext_vector_type(8)));
typedef float  f32x4  __attribute__((ext_vector_type(4)));
typedef float  f32x16 __attribute__((ext_vector_type(16)));

#define S_LEN 2048
#define EMB   2048
#define NH    16
#define NKV   4
#define HD    128
#define FQKV  3072  /* NH*HD + 2*NKV*HD */

__device__ __forceinline__ f32x4 mfma16(bf16x8 a, bf16x8 b, f32x4 c) {
  return __builtin_amdgcn_mfma_f32_16x16x32_bf16(a, b, c, 0, 0, 0);
}
__device__ __forceinline__ f32x16 mfma32(bf16x8 a, bf16x8 b, f32x16 c) {
  return __builtin_amdgcn_mfma_f32_32x32x16_bf16(a, b, c, 0, 0, 0);
}
__device__ __forceinline__ f32x16 zero16() {
  f32x16 v;
#pragma unroll
  for (int i = 0; i < 16; ++i) v[i] = 0.f;
  return v;
}

// ---------------- f32 -> bf16 convert, 4-wide ----------------
__global__ void cvt_kernel(const float* __restrict__ in, bf16* __restrict__ out, int n4) {
  int i = blockIdx.x * blockDim.x + threadIdx.x;
  const int stride = gridDim.x * blockDim.x;
  for (; i < n4; i += stride) {
    float4 v = reinterpret_cast<const float4*>(in)[i];
    bf16x4 o;
    o[0] = (bf16)v.x; o[1] = (bf16)v.y; o[2] = (bf16)v.z; o[3] = (bf16)v.w;
    reinterpret_cast<bf16x4*>(out)[i] = o;
  }
}

// ---------------- GEMM: C[M][N] = A[M][K] * B[N][K]^T (both row-major in K) ----------------
// mode 0: fused RoPE/split epilogue -> qb[h][s][d], kb[kh][s][d],
//         vtb = V in PV-fragment-ready layout: vf[kh][tile][d][32 perm kv]
// mode 1: plain f32 store to outf[row*N + col]
__global__ __launch_bounds__(256, 2) void gemm_bt(
    const bf16* __restrict__ A, const bf16* __restrict__ B,
    int M, int N, int K, int mode,
    bf16* __restrict__ qb, bf16* __restrict__ kb, bf16* __restrict__ vtb,
    float* __restrict__ outf)
{
  __shared__ __align__(16) bf16 As[128 * 64];
  __shared__ __align__(16) bf16 Bs[128 * 64];
  const int tid = threadIdx.x;
  const int w  = tid >> 6;
  const int l  = tid & 63;
  const int li = l & 15, lh = l >> 4;
  const int m0 = blockIdx.y * 128, n0 = blockIdx.x * 128;

  f32x4 acc[2][8];
#pragma unroll
  for (int i = 0; i < 2; ++i)
#pragma unroll
    for (int j = 0; j < 8; ++j) acc[i][j] = f32x4{0.f, 0.f, 0.f, 0.f};

  const int srow = l >> 3;   // row within an 8-row staging group
  const int schk = l & 7;    // 16B chunk within a 64-col row

  for (int k0 = 0; k0 < K; k0 += 64) {
#pragma unroll
    for (int i = 0; i < 4; ++i) {
      const int row = i * 32 + w * 8 + srow;
      const int sch = schk ^ (row & 7);
      const bf16* ga = A + (size_t)(m0 + row) * K + (k0 + sch * 8);
      const bf16* gb = B + (size_t)(n0 + row) * K + (k0 + sch * 8);
      bf16* la = As + (i * 32 + w * 8) * 64;
      bf16* lb = Bs + (i * 32 + w * 8) * 64;
      __builtin_amdgcn_global_load_lds((const __attribute__((address_space(1))) void*)ga,
                                       (__attribute__((address_space(3))) void*)la, 16, 0, 0);
      __builtin_amdgcn_global_load_lds((const __attribute__((address_space(1))) void*)gb,
                                       (__attribute__((address_space(3))) void*)lb, 16, 0, 0);
    }
    __syncthreads();
#pragma unroll
    for (int kc = 0; kc < 2; ++kc) {
      bf16x8 afr[2], bfr[8];
#pragma unroll
      for (int mt = 0; mt < 2; ++mt) {
        const int mr = w * 32 + mt * 16 + li;
        const int c  = (kc * 4 + lh) ^ (mr & 7);
        afr[mt] = *reinterpret_cast<const bf16x8*>((const char*)As + mr * 128 + c * 16);
      }
#pragma unroll
      for (int nt = 0; nt < 8; ++nt) {
        const int nr = nt * 16 + li;
        const int c  = (kc * 4 + lh) ^ (nr & 7);
        bfr[nt] = *reinterpret_cast<const bf16x8*>((const char*)Bs + nr * 128 + c * 16);
      }
#pragma unroll
      for (int nt = 0; nt < 8; ++nt) {
        acc[0][nt] = mfma16(afr[0], bfr[nt], acc[0][nt]);
        acc[1][nt] = mfma16(afr[1], bfr[nt], acc[1][nt]);
      }
    }
    __syncthreads();
  }

  // ---- epilogue ----
  const int row_base = m0 + w * 32;
  if (mode == 1) {
#pragma unroll
    for (int mt = 0; mt < 2; ++mt)
#pragma unroll
      for (int nt = 0; nt < 8; ++nt)
#pragma unroll
        for (int r = 0; r < 4; ++r) {
          const int sr = row_base + mt * 16 + lh * 4 + r;
          const int sc = n0 + nt * 16 + li;
          outf[(size_t)sr * N + sc] = acc[mt][nt][r];
        }
  } else {
    int seg, hh;
    if (n0 < NH * HD)            { seg = 0; hh = n0 >> 7; }
    else if (n0 < (NH + NKV) * HD){ seg = 1; hh = (n0 - NH * HD) >> 7; }
    else                          { seg = 2; hh = (n0 - (NH + NKV) * HD) >> 7; }

    if (seg == 2) {
      // V -> fragment-ready layout vf[kh][T][d][32]:
      // elems [0..7]=kv{0-3,8-11}, [8..15]={16-19,24-27}, [16..23]={4-7,12-15}, [24..31]={20-23,28-31}
      const int T = row_base >> 5;            // 32-row kv tile (same for mt=0,1)
#pragma unroll
      for (int mt = 0; mt < 2; ++mt) {
        const int qp = mt * 4 + lh;           // ss>>2, ss = mt*16+lh*4+r
        const int pq = (qp >> 1) + (qp & 1) * 4;
#pragma unroll
        for (int nt = 0; nt < 8; ++nt) {
          const int d = nt * 16 + li;
          bf16x4 pk;
#pragma unroll
          for (int r = 0; r < 4; ++r) pk[r] = (bf16)acc[mt][nt][r];
          *reinterpret_cast<bf16x4*>(
              vtb + ((size_t)(hh * 64 + T) * 128 + d) * 32 + pq * 4) = pk;
        }
      }
    } else {  // Q or K: RoPE (+ 1/sqrt(D) folded into Q)
      float invf[4];
#pragma unroll
      for (int j = 0; j < 4; ++j)
        invf[j] = exp2f(-(float)(j * 16 + li) * (13.287712379549449f / 64.0f)); // 10000^(-i/64)
      bf16* dst = (seg == 0) ? (qb + (size_t)hh * S_LEN * HD)
                             : (kb + (size_t)hh * S_LEN * HD);
      const float qscale = (seg == 0) ? 0.08838834764831845f : 1.0f;
#pragma unroll
      for (int mt = 0; mt < 2; ++mt)
#pragma unroll
        for (int r = 0; r < 4; ++r) {
          const int spos = row_base + mt * 16 + lh * 4 + r;
          float cs[4], sn[4];
#pragma unroll
          for (int j = 0; j < 4; ++j) sincosf((float)spos * invf[j], &sn[j], &cs[j]);
#pragma unroll
          for (int nt = 0; nt < 8; ++nt) {
            const int d = nt * 16 + li;
            const int j = nt & 3;
            const float x = acc[mt][nt][r];
            const float prt = acc[mt][nt ^ 4][r];
            const float rot = (nt < 4) ? -prt : prt;
            const float y = (x * cs[j] + rot * sn[j]) * qscale;
            dst[(size_t)spos * HD + d] = (bf16)y;
          }
        }
    }
  }
}

// ---------------- flash attention: persistent blocks + work queue ----------------
// 768 blocks (= 3 resident/CU at ~148 combined VGPR+AGPR). Items pulled via
// atomicAdd: item i -> (qt = 63 - i/16, h = i%16), longest q-tiles first.
// Within a block: 4 waves on the same 32 q-rows, wave w takes kv-tiles
// kv0 = w*32 + 128t (in-block split), merged through LDS. Math as r6.
__global__ __launch_bounds__(256, 3) void attn_kernel(
    const bf16* __restrict__ qb, const bf16* __restrict__ kb, const bf16* __restrict__ vtb,
    bf16* __restrict__ ctx, int* __restrict__ wcnt)
{
  __shared__ float Ml[4][32], Ll[4][32], Lgl[32];
  __shared__ float Obuf[32][129];   // stride 129: conflict-free column writes
  __shared__ int sitem;

  const int tid = threadIdx.x;
  const int w  = tid >> 6;
  const int l  = tid & 63;
  const int lq = l & 31;     // q index within tile (C col / B row)
  const int hi = l >> 5;     // lane half (C row group / k-slot group)

  const float L2E = 1.4426950408889634f;
  const float BIG = -3.0e38f;   // finite mask value: no NaN paths

  for (;;) {
    if (tid == 0) sitem = atomicAdd(wcnt, 1);
    __syncthreads();              // also fences LDS reuse across items
    const int item = sitem;
    if (item >= S_LEN / 32 * NH) break;

    const int qt = 63 - (item >> 4);   // longest first
    const int h  = item & 15;
    const int q0 = qt * 32;
    const int kh = h >> 2;             // rep = 4

    const bf16* Qh = qb + (size_t)h * S_LEN * HD;
    const bf16* Kh = kb + (size_t)kh * S_LEN * HD;
    const bf16* Vf = vtb + (size_t)kh * S_LEN * HD;   // fragment-ready layout

    // hoist Q fragments: lane -> q-row (q0+lq), d = kc*16 + hi*8 + {0..7}
    bf16x8 qfr[8];
#pragma unroll
    for (int kc = 0; kc < 8; ++kc)
      qfr[kc] = *reinterpret_cast<const bf16x8*>(Qh + (size_t)(q0 + lq) * HD + kc * 16 + hi * 8);

    f32x16 o[4];
#pragma unroll
    for (int dt = 0; dt < 4; ++dt) o[dt] = zero16();
    float mrow = BIG, lrow = 0.f;

    for (int kv0 = w * 32; kv0 < q0 + 32; kv0 += 128) {
      // ---- stage all K and V fragments for this tile (16 loads, then compute) ----
      const bf16* krow_p = Kh + (size_t)(kv0 + lq) * HD + hi * 8;
      bf16x8 kf[8];
#pragma unroll
      for (int kc = 0; kc < 8; ++kc)
        kf[kc] = *reinterpret_cast<const bf16x8*>(krow_p + kc * 16);
      const bf16* vbase = Vf + ((size_t)(kv0 >> 5) * 128 + lq) * 32 + hi * 16;
      bf16x8 va[8];
#pragma unroll
      for (int dt = 0; dt < 4; ++dt) {
        va[2 * dt]     = *reinterpret_cast<const bf16x8*>(vbase + (size_t)(dt * 32) * 32);
        va[2 * dt + 1] = *reinterpret_cast<const bf16x8*>(vbase + (size_t)(dt * 32) * 32 + 8);
      }
      // ---- QK^T: S^T[kv][q], two chains of 4 ----
      f32x16 sa = zero16(), sb = zero16();
#pragma unroll
      for (int kc = 0; kc < 4; ++kc) {
        sa = mfma32(kf[kc], qfr[kc], sa);
        sb = mfma32(kf[kc + 4], qfr[kc + 4], sb);
      }
      f32x16 s = sa + sb;
      // ---- causal mask (diagonal tiles only) ----
      const int q = q0 + lq;
      if (kv0 + 31 > q0) {
#pragma unroll
        for (int r = 0; r < 16; ++r) {
          const int kvv = (r & 3) + 8 * (r >> 2) + 4 * hi;
          if (kv0 + kvv > q) s[r] = BIG;
        }
      }
      // ---- in-register online softmax with defer-max (THR=8) ----
      float pm = s[0];
#pragma unroll
      for (int r = 1; r < 16; ++r) pm = fmaxf(pm, s[r]);
      pm = fmaxf(pm, __shfl_xor(pm, 32));
      if (__any(pm > mrow + 8.f)) {
        const float mnew = fmaxf(mrow, pm);
        const float sc = (mrow < -1.0e37f) ? 0.f : exp2f((mrow - mnew) * L2E);
        mrow = mnew;
        lrow *= sc;
#pragma unroll
        for (int dt = 0; dt < 4; ++dt) o[dt] = o[dt] * sc;
      }
      bf16x8 pb0, pb1;
      float tsum = 0.f;
#pragma unroll
      for (int r = 0; r < 8; ++r) {
        const float pv = exp2f((s[r] - mrow) * L2E);
        tsum += pv; pb0[r] = (bf16)pv;
      }
#pragma unroll
      for (int r = 0; r < 8; ++r) {
        const float pv = exp2f((s[8 + r] - mrow) * L2E);
        tsum += pv; pb1[r] = (bf16)pv;
      }
      tsum += __shfl_xor(tsum, 32);
      lrow += tsum;
      // ---- PV: O^T[d][q] += V^T[d][kv] * P, staged V ----
#pragma unroll
      for (int dt = 0; dt < 4; ++dt) {
        o[dt] = mfma32(va[2 * dt], pb0, o[dt]);
        o[dt] = mfma32(va[2 * dt + 1], pb1, o[dt]);
      }
    }

    // ---- merge the 4 KV-split partials (shared Obuf, serialized passes) ----
    if (hi == 0) { Ml[w][lq] = mrow; Ll[w][lq] = lrow; }
    __syncthreads();
    const float m0v = Ml[0][lq], m1v = Ml[1][lq], m2v = Ml[2][lq], m3v = Ml[3][lq];
    const float mg = fmaxf(fmaxf(m0v, m1v), fmaxf(m2v, m3v));
    const float lg = Ll[0][lq] * exp2f((m0v - mg) * L2E)
                   + Ll[1][lq] * exp2f((m1v - mg) * L2E)
                   + Ll[2][lq] * exp2f((m2v - mg) * L2E)
                   + Ll[3][lq] * exp2f((m3v - mg) * L2E);
    const float sc2 = (mrow < -1.0e37f) ? 0.f : exp2f((mrow - mg) * L2E);
    if (w == 0 && hi == 0) Lgl[lq] = lg;
#pragma unroll
    for (int pass = 0; pass < 4; ++pass) {
      if (w == pass) {
#pragma unroll
        for (int dt = 0; dt < 4; ++dt)
#pragma unroll
          for (int r = 0; r < 16; ++r) {
            const int d = dt * 32 + (r & 3) + 8 * (r >> 2) + 4 * hi;
            const float v = o[dt][r] * sc2;
            if (pass == 0) Obuf[lq][d] = v; else Obuf[lq][d] += v;
          }
      }
      __syncthreads();
    }
    // ---- epilogue: 256 threads, row = tid>>3, 16 d each ----
    {
      const int row = tid >> 3;
      const int d0 = (tid & 7) * 16;
      const float linv = 1.0f / Lgl[row];
      bf16x8 pk0, pk1;
#pragma unroll
      for (int j = 0; j < 8; ++j) {
        pk0[j] = (bf16)(Obuf[row][d0 + j] * linv);
        pk1[j] = (bf16)(Obuf[row][d0 + 8 + j] * linv);
      }
      bf16* dst = ctx + (size_t)(q0 + row) * (NH * HD) + h * HD + d0;
      *reinterpret_cast<bf16x8*>(dst) = pk0;
      *reinterpret_cast<bf16x8*>(dst + 8) = pk1;
    }
  }
}

extern "C" void kernel_launch(void* const* d_in, const int* in_sizes, int n_in,
                              void* d_out, int out_size, void* d_ws, size_t ws_size,
                              hipStream_t stream)
{
  const float* x       = (const float*)d_in[0];
  const float* w_qkv   = (const float*)d_in[1];
  const float* w_dense = (const float*)d_in[2];
  float* out = (float*)d_out;

  char* ws = (char*)d_ws;
  size_t off = 0;
  bf16* xb    = (bf16*)(ws + off); off += (size_t)S_LEN * EMB * 2;
  bf16* wqkvb = (bf16*)(ws + off); off += (size_t)FQKV * EMB * 2;
  bf16* wdb   = (bf16*)(ws + off); off += (size_t)EMB * EMB * 2;
  bf16* qbuf  = (bf16*)(ws + off); off += (size_t)NH  * S_LEN * HD * 2;
  bf16* kbuf  = (bf16*)(ws + off); off += (size_t)NKV * S_LEN * HD * 2;
  bf16* vfbuf = (bf16*)(ws + off); off += (size_t)NKV * HD * S_LEN * 2;
  bf16* ctxb  = (bf16*)(ws + off); off += (size_t)S_LEN * NH * HD * 2;
  int*  wcnt  = (int*)(ws + off);  off += 128;
  (void)ws_size; (void)in_sizes; (void)n_in; (void)out_size;

  cvt_kernel<<<2048, 256, 0, stream>>>(x,       xb,    S_LEN * EMB / 4);
  cvt_kernel<<<2048, 256, 0, stream>>>(w_qkv,   wqkvb, FQKV * EMB / 4);
  cvt_kernel<<<2048, 256, 0, stream>>>(w_dense, wdb,   EMB * EMB / 4);

  gemm_bt<<<dim3(FQKV / 128, S_LEN / 128), 256, 0, stream>>>(
      xb, wqkvb, S_LEN, FQKV, EMB, 0, qbuf, kbuf, vfbuf, nullptr);

  hipMemsetAsync(wcnt, 0, sizeof(int), stream);

  attn_kernel<<<768, 256, 0, stream>>>(qbuf, kbuf, vfbuf, ctxb, wcnt);

  gemm_bt<<<dim3(EMB / 128, S_LEN / 128), 256, 0, stream>>>(
      ctxb, wdb, S_LEN, EMB, NH * HD, 1, nullptr, nullptr, nullptr, out);
}

// Round 8
// 167.263 us; speedup vs baseline: 1.4730x; 1.1218x over previous
//
#include <hip/hip_runtime.h>
#include <hip/hip_bf16.h>
#include <math.h>

typedef __bf16 bf16;
typedef __bf16 bf16x4 __attribute__((ext_vector_type(4)));
typedef __bf16 bf16x8 __attribute__((ext_vector_type(8)));
typedef float  f32x4  __attribute__((ext_vector_type(4)));
typedef float  f32x16 __attribute__((ext_vector_type(16)));

#define S_LEN 2048
#define EMB   2048
#define NH    16
#define NKV   4
#define HD    128
#define FQKV  3072  /* NH*HD + 2*NKV*HD */

__device__ __forceinline__ f32x4 mfma16(bf16x8 a, bf16x8 b, f32x4 c) {
  return __builtin_amdgcn_mfma_f32_16x16x32_bf16(a, b, c, 0, 0, 0);
}
__device__ __forceinline__ f32x16 mfma32(bf16x8 a, bf16x8 b, f32x16 c) {
  return __builtin_amdgcn_mfma_f32_32x32x16_bf16(a, b, c, 0, 0, 0);
}
__device__ __forceinline__ f32x16 zero16() {
  f32x16 v;
#pragma unroll
  for (int i = 0; i < 16; ++i) v[i] = 0.f;
  return v;
}

// ---------------- f32 -> bf16 convert, 4-wide ----------------
__global__ void cvt_kernel(const float* __restrict__ in, bf16* __restrict__ out, int n4) {
  int i = blockIdx.x * blockDim.x + threadIdx.x;
  const int stride = gridDim.x * blockDim.x;
  for (; i < n4; i += stride) {
    float4 v = reinterpret_cast<const float4*>(in)[i];
    bf16x4 o;
    o[0] = (bf16)v.x; o[1] = (bf16)v.y; o[2] = (bf16)v.z; o[3] = (bf16)v.w;
    reinterpret_cast<bf16x4*>(out)[i] = o;
  }
}

// ---------------- GEMM: C[M][N] = A[M][K] * B[N][K]^T ----------------
// mode 0: fused RoPE/split epilogue. Q,K,V all stored in fragment-ready TILED
// layouts (per head, per 32-row tile T, elem addr = T*4096 + slot*256 + lq*8 + e)
// so every attention load is a fully-coalesced contiguous 1KB wave-load:
//   Q/K: slot = kc*2 + hi            (kc = d>>4, hi = (d>>3)&1, e = d&7)
//   V:   slot = (dt*2+j)*2 + hi, holding V[kv0+kvslot(j,hi,e)][dt*32+lq],
//        kvslot = (e&3) + 8*(e>>2) + 4*hi + 16*j
// mode 1: plain f32 store to outf[row*N + col]
__global__ __launch_bounds__(256, 2) void gemm_bt(
    const bf16* __restrict__ A, const bf16* __restrict__ B,
    int M, int N, int K, int mode,
    bf16* __restrict__ qb, bf16* __restrict__ kb, bf16* __restrict__ vtb,
    float* __restrict__ outf)
{
  __shared__ __align__(16) bf16 As[128 * 64];
  __shared__ __align__(16) bf16 Bs[128 * 64];
  const int tid = threadIdx.x;
  const int w  = tid >> 6;
  const int l  = tid & 63;
  const int li = l & 15, lh = l >> 4;
  const int m0 = blockIdx.y * 128, n0 = blockIdx.x * 128;

  f32x4 acc[2][8];
#pragma unroll
  for (int i = 0; i < 2; ++i)
#pragma unroll
    for (int j = 0; j < 8; ++j) acc[i][j] = f32x4{0.f, 0.f, 0.f, 0.f};

  const int srow = l >> 3;   // row within an 8-row staging group
  const int schk = l & 7;    // 16B chunk within a 64-col row

  for (int k0 = 0; k0 < K; k0 += 64) {
#pragma unroll
    for (int i = 0; i < 4; ++i) {
      const int row = i * 32 + w * 8 + srow;
      const int sch = schk ^ (row & 7);
      const bf16* ga = A + (size_t)(m0 + row) * K + (k0 + sch * 8);
      const bf16* gb = B + (size_t)(n0 + row) * K + (k0 + sch * 8);
      bf16* la = As + (i * 32 + w * 8) * 64;
      bf16* lb = Bs + (i * 32 + w * 8) * 64;
      __builtin_amdgcn_global_load_lds((const __attribute__((address_space(1))) void*)ga,
                                       (__attribute__((address_space(3))) void*)la, 16, 0, 0);
      __builtin_amdgcn_global_load_lds((const __attribute__((address_space(1))) void*)gb,
                                       (__attribute__((address_space(3))) void*)lb, 16, 0, 0);
    }
    __syncthreads();
#pragma unroll
    for (int kc = 0; kc < 2; ++kc) {
      bf16x8 afr[2], bfr[8];
#pragma unroll
      for (int mt = 0; mt < 2; ++mt) {
        const int mr = w * 32 + mt * 16 + li;
        const int c  = (kc * 4 + lh) ^ (mr & 7);
        afr[mt] = *reinterpret_cast<const bf16x8*>((const char*)As + mr * 128 + c * 16);
      }
#pragma unroll
      for (int nt = 0; nt < 8; ++nt) {
        const int nr = nt * 16 + li;
        const int c  = (kc * 4 + lh) ^ (nr & 7);
        bfr[nt] = *reinterpret_cast<const bf16x8*>((const char*)Bs + nr * 128 + c * 16);
      }
#pragma unroll
      for (int nt = 0; nt < 8; ++nt) {
        acc[0][nt] = mfma16(afr[0], bfr[nt], acc[0][nt]);
        acc[1][nt] = mfma16(afr[1], bfr[nt], acc[1][nt]);
      }
    }
    __syncthreads();
  }

  // ---- epilogue ----
  const int row_base = m0 + w * 32;
  if (mode == 1) {
#pragma unroll
    for (int mt = 0; mt < 2; ++mt)
#pragma unroll
      for (int nt = 0; nt < 8; ++nt)
#pragma unroll
        for (int r = 0; r < 4; ++r) {
          const int sr = row_base + mt * 16 + lh * 4 + r;
          const int sc = n0 + nt * 16 + li;
          outf[(size_t)sr * N + sc] = acc[mt][nt][r];
        }
  } else {
    int seg, hh;
    if (n0 < NH * HD)            { seg = 0; hh = n0 >> 7; }
    else if (n0 < (NH + NKV) * HD){ seg = 1; hh = (n0 - NH * HD) >> 7; }
    else                          { seg = 2; hh = (n0 - (NH + NKV) * HD) >> 7; }

    const int T = row_base >> 5;          // 32-row tile index (constant per wave)
    if (seg == 2) {
      // V tiled store: acc[mt][nt][r] = V[spos][d], spos = row_base + qp*4 + r,
      // qp = mt*4+lh; d = nt*16+li -> dt = nt>>1, lqv = (nt&1)*16+li.
      // j=(qp>>2)&1, hiv=qp&1, e = 4*((qp>>1)&1) + r  (4 consecutive r -> bf16x4)
      bf16* vdst = vtb + (size_t)hh * S_LEN * HD + (size_t)T * 4096;
#pragma unroll
      for (int mt = 0; mt < 2; ++mt) {
        const int qp = mt * 4 + lh;
        const int jj = (qp >> 2) & 1, hiv = qp & 1, ebase = 4 * ((qp >> 1) & 1);
#pragma unroll
        for (int nt = 0; nt < 8; ++nt) {
          const int dt = nt >> 1;
          const int lqv = (nt & 1) * 16 + li;
          bf16x4 pk;
#pragma unroll
          for (int r = 0; r < 4; ++r) pk[r] = (bf16)acc[mt][nt][r];
          *reinterpret_cast<bf16x4*>(
              vdst + ((dt * 2 + jj) * 2 + hiv) * 256 + lqv * 8 + ebase) = pk;
        }
      }
    } else {  // Q or K: RoPE (+ 1/sqrt(D) folded into Q), tiled store
      float invf[4];
#pragma unroll
      for (int j = 0; j < 4; ++j)
        invf[j] = exp2f(-(float)(j * 16 + li) * (13.287712379549449f / 64.0f)); // 10000^(-i/64)
      bf16* dst = ((seg == 0) ? (qb + (size_t)hh * S_LEN * HD)
                              : (kb + (size_t)hh * S_LEN * HD)) + (size_t)T * 4096;
      const float qscale = (seg == 0) ? 0.08838834764831845f : 1.0f;
      const int hi2 = li >> 3, e2 = li & 7;
#pragma unroll
      for (int mt = 0; mt < 2; ++mt)
#pragma unroll
        for (int r = 0; r < 4; ++r) {
          const int spos = row_base + mt * 16 + lh * 4 + r;
          const int lqr  = spos & 31;
          float cs[4], sn[4];
#pragma unroll
          for (int j = 0; j < 4; ++j) sincosf((float)spos * invf[j], &sn[j], &cs[j]);
#pragma unroll
          for (int nt = 0; nt < 8; ++nt) {
            const int j = nt & 3;
            const float x = acc[mt][nt][r];
            const float prt = acc[mt][nt ^ 4][r];
            const float rot = (nt < 4) ? -prt : prt;
            const float y = (x * cs[j] + rot * sn[j]) * qscale;
            dst[(nt * 2 + hi2) * 256 + lqr * 8 + e2] = (bf16)y;
          }
        }
    }
  }
}

// ---------------- flash attention: persistent queue, tiled coalesced loads ----------------
// 768 blocks. Item i -> (qt = 63 - i/16, h = i%16). 4 waves on the same 32
// q-rows; wave w takes kv-tiles kv0 = w*32 + 128t. All K/Q/V loads are
// contiguous 1KB wave-loads from the tiled layouts. V issued at loop top
// (latency hidden under QK^T + softmax). Math identical to r6.
__global__ __launch_bounds__(256, 3) void attn_kernel(
    const bf16* __restrict__ qb, const bf16* __restrict__ kb, const bf16* __restrict__ vtb,
    bf16* __restrict__ ctx, int* __restrict__ wcnt)
{
  __shared__ float Ml[4][32], Ll[4][32], Lgl[32];
  __shared__ float Obuf[32][129];
  __shared__ int sitem;

  const int tid = threadIdx.x;
  const int w  = tid >> 6;
  const int l  = tid & 63;
  const int lq = l & 31;
  const int hi = l >> 5;

  const float L2E = 1.4426950408889634f;
  const float BIG = -3.0e38f;

  for (;;) {
    if (tid == 0) sitem = atomicAdd(wcnt, 1);
    __syncthreads();
    const int item = sitem;
    if (item >= S_LEN / 32 * NH) break;

    const int qt = 63 - (item >> 4);
    const int h  = item & 15;
    const int q0 = qt * 32;
    const int kh = h >> 2;

    const bf16* Qh = qb + (size_t)h * S_LEN * HD;
    const bf16* Kh = kb + (size_t)kh * S_LEN * HD;
    const bf16* Vh = vtb + (size_t)kh * S_LEN * HD;

    // hoist Q fragments (coalesced 1KB per load)
    const bf16* qtile = Qh + (size_t)qt * 4096;
    bf16x8 qfr[8];
#pragma unroll
    for (int kc = 0; kc < 8; ++kc)
      qfr[kc] = *reinterpret_cast<const bf16x8*>(qtile + (kc * 2 + hi) * 256 + lq * 8);

    f32x16 o[4];
#pragma unroll
    for (int dt = 0; dt < 4; ++dt) o[dt] = zero16();
    float mrow = BIG, lrow = 0.f;

    for (int kv0 = w * 32; kv0 < q0 + 32; kv0 += 128) {
      const bf16* ktile = Kh + (size_t)(kv0 >> 5) * 4096;
      const bf16* vtile = Vh + (size_t)(kv0 >> 5) * 4096;
      // ---- issue V first (needed only after softmax), then K ----
      bf16x8 va[8];
#pragma unroll
      for (int sv = 0; sv < 8; ++sv)
        va[sv] = *reinterpret_cast<const bf16x8*>(vtile + (sv * 2 + hi) * 256 + lq * 8);
      bf16x8 kf[8];
#pragma unroll
      for (int kc = 0; kc < 8; ++kc)
        kf[kc] = *reinterpret_cast<const bf16x8*>(ktile + (kc * 2 + hi) * 256 + lq * 8);
      // ---- QK^T: S^T[kv][q], two chains of 4 ----
      f32x16 sa = zero16(), sb = zero16();
#pragma unroll
      for (int kc = 0; kc < 4; ++kc) {
        sa = mfma32(kf[kc], qfr[kc], sa);
        sb = mfma32(kf[kc + 4], qfr[kc + 4], sb);
      }
      f32x16 s = sa + sb;
      // ---- causal mask (diagonal tiles only) ----
      const int q = q0 + lq;
      if (kv0 + 31 > q0) {
#pragma unroll
        for (int r = 0; r < 16; ++r) {
          const int kvv = (r & 3) + 8 * (r >> 2) + 4 * hi;
          if (kv0 + kvv > q) s[r] = BIG;
        }
      }
      // ---- in-register online softmax with defer-max (THR=8) ----
      float pm = s[0];
#pragma unroll
      for (int r = 1; r < 16; ++r) pm = fmaxf(pm, s[r]);
      pm = fmaxf(pm, __shfl_xor(pm, 32));
      if (__any(pm > mrow + 8.f)) {
        const float mnew = fmaxf(mrow, pm);
        const float sc = (mrow < -1.0e37f) ? 0.f : exp2f((mrow - mnew) * L2E);
        mrow = mnew;
        lrow *= sc;
#pragma unroll
        for (int dt = 0; dt < 4; ++dt) o[dt] = o[dt] * sc;
      }
      bf16x8 pb0, pb1;
      float tsum = 0.f;
#pragma unroll
      for (int r = 0; r < 8; ++r) {
        const float pv = exp2f((s[r] - mrow) * L2E);
        tsum += pv; pb0[r] = (bf16)pv;
      }
#pragma unroll
      for (int r = 0; r < 8; ++r) {
        const float pv = exp2f((s[8 + r] - mrow) * L2E);
        tsum += pv; pb1[r] = (bf16)pv;
      }
      tsum += __shfl_xor(tsum, 32);
      lrow += tsum;
      // ---- PV ----
#pragma unroll
      for (int dt = 0; dt < 4; ++dt) {
        o[dt] = mfma32(va[2 * dt], pb0, o[dt]);
        o[dt] = mfma32(va[2 * dt + 1], pb1, o[dt]);
      }
    }

    // ---- merge the 4 KV-split partials ----
    if (hi == 0) { Ml[w][lq] = mrow; Ll[w][lq] = lrow; }
    __syncthreads();
    const float m0v = Ml[0][lq], m1v = Ml[1][lq], m2v = Ml[2][lq], m3v = Ml[3][lq];
    const float mg = fmaxf(fmaxf(m0v, m1v), fmaxf(m2v, m3v));
    const float lg = Ll[0][lq] * exp2f((m0v - mg) * L2E)
                   + Ll[1][lq] * exp2f((m1v - mg) * L2E)
                   + Ll[2][lq] * exp2f((m2v - mg) * L2E)
                   + Ll[3][lq] * exp2f((m3v - mg) * L2E);
    const float sc2 = (mrow < -1.0e37f) ? 0.f : exp2f((mrow - mg) * L2E);
    if (w == 0 && hi == 0) Lgl[lq] = lg;
#pragma unroll
    for (int pass = 0; pass < 4; ++pass) {
      if (w == pass) {
#pragma unroll
        for (int dt = 0; dt < 4; ++dt)
#pragma unroll
          for (int r = 0; r < 16; ++r) {
            const int d = dt * 32 + (r & 3) + 8 * (r >> 2) + 4 * hi;
            const float v = o[dt][r] * sc2;
            if (pass == 0) Obuf[lq][d] = v; else Obuf[lq][d] += v;
          }
      }
      __syncthreads();
    }
    // ---- epilogue ----
    {
      const int row = tid >> 3;
      const int d0 = (tid & 7) * 16;
      const float linv = 1.0f / Lgl[row];
      bf16x8 pk0, pk1;
#pragma unroll
      for (int j = 0; j < 8; ++j) {
        pk0[j] = (bf16)(Obuf[row][d0 + j] * linv);
        pk1[j] = (bf16)(Obuf[row][d0 + 8 + j] * linv);
      }
      bf16* dst = ctx + (size_t)(q0 + row) * (NH * HD) + h * HD + d0;
      *reinterpret_cast<bf16x8*>(dst) = pk0;
      *reinterpret_cast<bf16x8*>(dst + 8) = pk1;
    }
  }
}

extern "C" void kernel_launch(void* const* d_in, const int* in_sizes, int n_in,
                              void* d_out, int out_size, void* d_ws, size_t ws_size,
                              hipStream_t stream)
{
  const float* x       = (const float*)d_in[0];
  const float* w_qkv   = (const float*)d_in[1];
  const float* w_dense = (const float*)d_in[2];
  float* out = (float*)d_out;

  char* ws = (char*)d_ws;
  size_t off = 0;
  bf16* xb    = (bf16*)(ws + off); off += (size_t)S_LEN * EMB * 2;
  bf16* wqkvb = (bf16*)(ws + off); off += (size_t)FQKV * EMB * 2;
  bf16* wdb   = (bf16*)(ws + off); off += (size_t)EMB * EMB * 2;
  bf16* qbuf  = (bf16*)(ws + off); off += (size_t)NH  * S_LEN * HD * 2;
  bf16* kbuf  = (bf16*)(ws + off); off += (size_t)NKV * S_LEN * HD * 2;
  bf16* vfbuf = (bf16*)(ws + off); off += (size_t)NKV * HD * S_LEN * 2;
  bf16* ctxb  = (bf16*)(ws + off); off += (size_t)S_LEN * NH * HD * 2;
  int*  wcnt  = (int*)(ws + off);  off += 128;
  (void)ws_size; (void)in_sizes; (void)n_in; (void)out_size;

  cvt_kernel<<<2048, 256, 0, stream>>>(x,       xb,    S_LEN * EMB / 4);
  cvt_kernel<<<2048, 256, 0, stream>>>(w_qkv,   wqkvb, FQKV * EMB / 4);
  cvt_kernel<<<2048, 256, 0, stream>>>(w_dense, wdb,   EMB * EMB / 4);

  gemm_bt<<<dim3(FQKV / 128, S_LEN / 128), 256, 0, stream>>>(
      xb, wqkvb, S_LEN, FQKV, EMB, 0, qbuf, kbuf, vfbuf, nullptr);

  hipMemsetAsync(wcnt, 0, sizeof(int), stream);

  attn_kernel<<<768, 256, 0, stream>>>(qbuf, kbuf, vfbuf, ctxb, wcnt);

  gemm_bt<<<dim3(EMB / 128, S_LEN / 128), 256, 0, stream>>>(
      ctxb, wdb, S_LEN, EMB, NH * HD, 1, nullptr, nullptr, nullptr, out);
}